// Round 1
// baseline (91.019 us; speedup 1.0000x reference)
//
#include <hip/hip_runtime.h>
#include <math.h>

// Problem constants (from reference setup_inputs): B=4, N=8192, F=8192, P=2048
#define Bn 4
#define Nn 8192
#define Fn 8192
#define Pn 2048
#define NCHUNK 128           // face chunks per batch
#define CH (Fn / NCHUNK)     // 64 faces per chunk; CH*4 floats == 256 == blockDim
#define MIN_DIST 0.1f

// ---------------- Kernel A: per-face precompute ----------------
// fd[b*F+f] = (nx*s, ny*s, nz*s, d*s) with d = MIN_DIST - dot(center, n),
// s = sqrt(||n||^2). Then signed' = dot(p, n*s) + d*s = s * (dot(p-c,n)+0.1),
// and signed'^2 == signed^2 * fn_sq (reference's sqdist), sign preserved.
__global__ __launch_bounds__(256)
void face_pre(const float* __restrict__ V, const float* __restrict__ FN,
              const int* __restrict__ Fidx, float4* __restrict__ fd) {
    int i = blockIdx.x * 256 + threadIdx.x;
    if (i >= Bn * Fn) return;
    int b = i / Fn;
    const int* fi = Fidx + (size_t)i * 3;
    int i0 = fi[0], i1 = fi[1], i2 = fi[2];
    const float* Vb = V + (size_t)b * Nn * 3;
    float cx = (Vb[i0*3+0] + Vb[i1*3+0] + Vb[i2*3+0]) / 3.0f;
    float cy = (Vb[i0*3+1] + Vb[i1*3+1] + Vb[i2*3+1]) / 3.0f;
    float cz = (Vb[i0*3+2] + Vb[i1*3+2] + Vb[i2*3+2]) / 3.0f;
    const float* n = FN + (size_t)i * 3;
    float nx = n[0], ny = n[1], nz = n[2];
    float d = MIN_DIST - (cx*nx + cy*ny + cz*nz);
    float s = sqrtf(nx*nx + ny*ny + nz*nz);
    fd[i] = make_float4(nx*s, ny*s, nz*s, d*s);
}

// ---------------- bool-storage probe ----------------
// exterior_flag is a jax bool array; harness may hand it to us as 1-byte bool
// or as int32. If int32 (values 0/1, little-endian), every byte at offset
// i%4!=0 is zero. Bernoulli(0.5) over 8192 elements makes the byte-mode test
// essentially certain. mode=1 -> 1-byte bools, mode=0 -> int32.
__global__ void detect_mode(const unsigned char* __restrict__ flags, int* __restrict__ mode) {
    __shared__ int cnt;
    if (threadIdx.x == 0) cnt = 0;
    __syncthreads();
    int local = 0;
    for (int i = threadIdx.x; i < Bn * Pn; i += 256)
        if ((i & 3) && flags[i]) local++;
    if (local) atomicAdd(&cnt, local);
    __syncthreads();
    if (threadIdx.x == 0) *mode = (cnt > 0) ? 1 : 0;
}

// ---------------- Kernel B: per (batch, face-chunk) min over points ----------
// Block = 256 threads, covers all 2048 points of one batch vs CH=64 faces.
// 8 points/thread in registers; faces staged in LDS (broadcast reads).
// Min tracked on raw fp32 bits with unsigned min: non-negative floats order as
// uints; negative signed (bits >= 0x80000000) can never beat the positive init,
// exactly implementing where(signed<0, BIG, .) and the all-negative case.
__global__ __launch_bounds__(256)
void chunk_min(const float* __restrict__ points, const float4* __restrict__ fd,
               unsigned* __restrict__ partials) {
    int c = blockIdx.x % NCHUNK;
    int b = blockIdx.x / NCHUNK;
    int tid = threadIdx.x;

    __shared__ float4 lf[CH];
    ((float*)lf)[tid] = ((const float*)(fd + (size_t)b * Fn + (size_t)c * CH))[tid];

    float px[8], py[8], pz[8];
    const float* pb = points + (size_t)b * Pn * 3;
#pragma unroll
    for (int k = 0; k < 8; ++k) {
        int p = tid + 256 * k;
        px[k] = pb[p*3+0]; py[k] = pb[p*3+1]; pz[k] = pb[p*3+2];
    }
    unsigned m[8];
#pragma unroll
    for (int k = 0; k < 8; ++k) m[k] = 0x7F7FFFFFu;  // FLT_MAX bits

    __syncthreads();

#pragma unroll 4
    for (int j = 0; j < CH; ++j) {
        float4 f = lf[j];
#pragma unroll
        for (int k = 0; k < 8; ++k) {
            float s = fmaf(px[k], f.x, fmaf(py[k], f.y, fmaf(pz[k], f.z, f.w)));
            unsigned su = __float_as_uint(s);
            m[k] = su < m[k] ? su : m[k];
        }
    }

    unsigned* out = partials + (size_t)c * (Bn * Pn) + (size_t)b * Pn;
#pragma unroll
    for (int k = 0; k < 8; ++k) out[tid + 256 * k] = m[k];
}

// ---------------- Kernel C: per-point reduce over chunks + flag + block sums --
__global__ __launch_bounds__(256)
void point_reduce(const unsigned* __restrict__ partials,
                  const unsigned char* __restrict__ flagsB,
                  const int* __restrict__ flagsI,
                  const int* __restrict__ mode,
                  float* __restrict__ blocksums) {
    int i = blockIdx.x * 256 + threadIdx.x;   // 0 .. B*P-1
    unsigned m = 0x7F7FFFFFu;
    for (int c = 0; c < NCHUNK; ++c) {
        unsigned v = partials[(size_t)c * (Bn * Pn) + i];
        m = v < m ? v : m;
    }
    float mf = __uint_as_float(m);
    int ext = (*mode) ? (flagsB[i] != 0) : (flagsI[i] != 0);
    // mf >= 1e9 means no face had signed >= 0 -> "inside" -> 0 (matches ref)
    float val = (ext && mf < 1e9f) ? mf * mf : 0.0f;

    // block reduction: wave shuffle (64 lanes) then across 4 waves via LDS
    for (int o = 32; o > 0; o >>= 1) val += __shfl_down(val, o);
    __shared__ float wsum[4];
    int lane = threadIdx.x & 63, wid = threadIdx.x >> 6;
    if (lane == 0) wsum[wid] = val;
    __syncthreads();
    if (threadIdx.x == 0)
        blocksums[blockIdx.x] = wsum[0] + wsum[1] + wsum[2] + wsum[3];
}

// ---------------- Kernel D: final scalar ----------------
__global__ void finalize(const float* __restrict__ blocksums, float* __restrict__ out) {
    float v = (threadIdx.x < (Bn * Pn) / 256) ? blocksums[threadIdx.x] : 0.0f;
    for (int o = 32; o > 0; o >>= 1) v += __shfl_down(v, o);
    if (threadIdx.x == 0) out[0] = v * (1.0f / (Bn * Pn)); // mean over P then B == /(B*P)
}

extern "C" void kernel_launch(void* const* d_in, const int* in_sizes, int n_in,
                              void* d_out, int out_size, void* d_ws, size_t ws_size,
                              hipStream_t stream) {
    const float* mesh_V  = (const float*)d_in[0];
    const float* points  = (const float*)d_in[1];
    const float* mesh_FN = (const float*)d_in[2];
    const int*   mesh_F  = (const int*)d_in[3];
    const void*  eflag   = d_in[4];
    float* out = (float*)d_out;

    char* ws = (char*)d_ws;
    const size_t faceBytes = (size_t)Bn * Fn * sizeof(float4);          // 512 KiB
    const size_t partBytes = (size_t)NCHUNK * Bn * Pn * sizeof(unsigned); // 4 MiB
    float4*   faceData  = (float4*)ws;
    unsigned* partials  = (unsigned*)(ws + faceBytes);
    float*    blocksums = (float*)(ws + faceBytes + partBytes);
    int*      mode      = (int*)(ws + faceBytes + partBytes + 256);

    face_pre<<<(Bn * Fn + 255) / 256, 256, 0, stream>>>(mesh_V, mesh_FN, mesh_F, faceData);
    detect_mode<<<1, 256, 0, stream>>>((const unsigned char*)eflag, mode);
    chunk_min<<<Bn * NCHUNK, 256, 0, stream>>>(points, faceData, partials);
    point_reduce<<<(Bn * Pn) / 256, 256, 0, stream>>>(partials,
                                                      (const unsigned char*)eflag,
                                                      (const int*)eflag, mode, blocksums);
    finalize<<<1, 64, 0, stream>>>(blocksums, out);
}

// Round 2
// 86.511 us; speedup vs baseline: 1.0521x; 1.0521x over previous
//
#include <hip/hip_runtime.h>
#include <math.h>

// Problem constants (from reference setup_inputs): B=4, N=8192, F=8192, P=2048
#define Bn 4
#define Nn 8192
#define Fn 8192
#define Pn 2048
#define NCHUNK 256           // face chunks per batch
#define CH (Fn / NCHUNK)     // 32 faces per chunk
#define PPT 8                // points per thread (Pn / 256)
#define MIN_DIST 0.1f
#define FLTMAX_BITS 0x7F7FFFFFu

typedef float v2f __attribute__((ext_vector_type(2)));

struct Meta { float acc; int cnt; int mode; };

// ---------------- Kernel 1: fused face-precompute + per-chunk point min -----
// Grid: Bn * NCHUNK = 1024 blocks, 256 threads.
// Block (b,c): precompute its CH=32 faces -> (n*s, d*s) in LDS, where
// d = MIN_DIST - dot(center,n), s = ||n||. Then signed' = dot(p,n*s)+d*s
// = s*(dot(p-c,n)+MIN_DIST), and signed'^2 == signed^2*fn_sq (ref sqdist),
// sign preserved. Each thread owns 8 points (as 4 float2 pairs -> v_pk_fma_f32)
// and min-tracks raw fp32 bits with unsigned min: non-negative floats order as
// uints; negative signed (bits >= 0x80000000) can never beat the FLT_MAX init,
// which exactly implements where(signed<0, BIG, .) + the all-negative case.
// Block 0 additionally: bool-vs-int32 storage probe for exterior_flag, and
// zero-init of the Meta accumulator used by kernel 2.
__global__ __launch_bounds__(256)
void chunk_min(const float* __restrict__ V, const float* __restrict__ FN,
               const int* __restrict__ Fidx, const float* __restrict__ points,
               const unsigned char* __restrict__ flags,
               unsigned* __restrict__ partials, Meta* __restrict__ meta) {
    int c = blockIdx.x & (NCHUNK - 1);
    int b = blockIdx.x >> 8;          // NCHUNK==256
    int tid = threadIdx.x;

    __shared__ float4 lf[CH];

    // --- face precompute (threads 0..CH-1) ---
    if (tid < CH) {
        int i = b * Fn + c * CH + tid;
        const int* fi = Fidx + (size_t)i * 3;
        int i0 = fi[0], i1 = fi[1], i2 = fi[2];
        const float* Vb = V + (size_t)b * Nn * 3;
        float cx = (Vb[i0*3+0] + Vb[i1*3+0] + Vb[i2*3+0]) * (1.0f/3.0f);
        float cy = (Vb[i0*3+1] + Vb[i1*3+1] + Vb[i2*3+1]) * (1.0f/3.0f);
        float cz = (Vb[i0*3+2] + Vb[i1*3+2] + Vb[i2*3+2]) * (1.0f/3.0f);
        const float* n = FN + (size_t)i * 3;
        float nx = n[0], ny = n[1], nz = n[2];
        float d = MIN_DIST - (cx*nx + cy*ny + cz*nz);
        float s = sqrtf(nx*nx + ny*ny + nz*nz);
        lf[tid] = make_float4(nx*s, ny*s, nz*s, d*s);
    }

    // --- load this thread's 8 points as 4 (pair) float2 vectors ---
    v2f px[PPT/2], py[PPT/2], pz[PPT/2];
    const float* pb = points + (size_t)b * Pn * 3;
#pragma unroll
    for (int k = 0; k < PPT/2; ++k) {
        int p0 = tid + 256 * (2*k);
        int p1 = p0 + 256;
        px[k] = (v2f){pb[p0*3+0], pb[p1*3+0]};
        py[k] = (v2f){pb[p0*3+1], pb[p1*3+1]};
        pz[k] = (v2f){pb[p0*3+2], pb[p1*3+2]};
    }
    unsigned m[PPT];
#pragma unroll
    for (int k = 0; k < PPT; ++k) m[k] = FLTMAX_BITS;

    __syncthreads();

#pragma unroll 4
    for (int j = 0; j < CH; ++j) {
        float4 f = lf[j];
        v2f fx = (v2f){f.x, f.x}, fy = (v2f){f.y, f.y},
            fz = (v2f){f.z, f.z}, fw = (v2f){f.w, f.w};
#pragma unroll
        for (int k = 0; k < PPT/2; ++k) {
#if __has_builtin(__builtin_elementwise_fma)
            v2f s = __builtin_elementwise_fma(px[k], fx,
                    __builtin_elementwise_fma(py[k], fy,
                    __builtin_elementwise_fma(pz[k], fz, fw)));
#else
            v2f s;
            s.x = fmaf(px[k].x, f.x, fmaf(py[k].x, f.y, fmaf(pz[k].x, f.z, f.w)));
            s.y = fmaf(px[k].y, f.x, fmaf(py[k].y, f.y, fmaf(pz[k].y, f.z, f.w)));
#endif
            unsigned sx = __float_as_uint(s.x);
            unsigned sy = __float_as_uint(s.y);
            m[2*k]   = sx < m[2*k]   ? sx : m[2*k];
            m[2*k+1] = sy < m[2*k+1] ? sy : m[2*k+1];
        }
    }

    // partials layout: [c][b*Pn + p] so kernel 2 reads coalesced rows
    unsigned* out = partials + (size_t)c * (Bn * Pn) + (size_t)b * Pn;
#pragma unroll
    for (int k = 0; k < PPT/2; ++k) {
        out[tid + 256 * (2*k)]     = m[2*k];
        out[tid + 256 * (2*k) + 256] = m[2*k+1];
    }

    // --- block 0 housekeeping: storage-mode probe + meta zero-init ---
    // exterior_flag is a jax bool array; it may arrive as 1-byte bool or as
    // int32 (0/1 little-endian). If int32, every byte at offset i%4!=0 is 0.
    // Bernoulli(0.5) over 8192 elems makes the probe essentially certain.
    if (blockIdx.x == 0) {
        __shared__ int cnt;
        if (tid == 0) cnt = 0;
        __syncthreads();
        int local = 0;
        for (int i = tid; i < Bn * Pn; i += 256)
            if ((i & 3) && flags[i]) local++;
        if (local) atomicAdd(&cnt, local);
        __syncthreads();
        if (tid == 0) {
            meta->mode = (cnt > 0) ? 1 : 0;   // 1 -> byte bools, 0 -> int32
            meta->acc = 0.0f;
            meta->cnt = 0;
        }
    }
}

// ---------------- Kernel 2: per-point reduce + flag + global mean -----------
// Grid: (Bn*Pn)/256 = 32 blocks. Thread i: min over NCHUNK partial rows
// (coalesced), apply exterior flag, square, block-reduce, then last-block
// arrive pattern produces the final scalar (no extra launch).
__global__ __launch_bounds__(256)
void point_reduce(const unsigned* __restrict__ partials,
                  const unsigned char* __restrict__ flagsB,
                  const int* __restrict__ flagsI,
                  Meta* __restrict__ meta, float* __restrict__ out) {
    int i = blockIdx.x * 256 + threadIdx.x;   // 0 .. B*P-1
    unsigned m = FLTMAX_BITS;
#pragma unroll 8
    for (int c = 0; c < NCHUNK; ++c) {
        unsigned v = partials[(size_t)c * (Bn * Pn) + i];
        m = v < m ? v : m;
    }
    int ext = (meta->mode) ? (flagsB[i] != 0) : (flagsI[i] != 0);
    float mf = __uint_as_float(m);
    // m == FLT_MAX bits -> no face had signed >= 0 -> "inside" -> 0 (ref match)
    float val = (ext && m < FLTMAX_BITS) ? mf * mf : 0.0f;

    // wave (64-lane) shuffle reduce, then across the 4 waves via LDS
    for (int o = 32; o > 0; o >>= 1) val += __shfl_down(val, o);
    __shared__ float wsum[4];
    int lane = threadIdx.x & 63, wid = threadIdx.x >> 6;
    if (lane == 0) wsum[wid] = val;
    __syncthreads();
    if (threadIdx.x == 0) {
        float s = wsum[0] + wsum[1] + wsum[2] + wsum[3];
        atomicAdd(&meta->acc, s);
        __threadfence();
        int ticket = atomicAdd(&meta->cnt, 1);
        if (ticket == gridDim.x - 1) {
            // all blocks' acc-adds are fenced before their cnt-add -> visible
            float total = atomicAdd(&meta->acc, 0.0f);  // atomic read
            out[0] = total * (1.0f / (Bn * Pn));  // mean over P then B
        }
    }
}

extern "C" void kernel_launch(void* const* d_in, const int* in_sizes, int n_in,
                              void* d_out, int out_size, void* d_ws, size_t ws_size,
                              hipStream_t stream) {
    const float* mesh_V  = (const float*)d_in[0];
    const float* points  = (const float*)d_in[1];
    const float* mesh_FN = (const float*)d_in[2];
    const int*   mesh_F  = (const int*)d_in[3];
    const void*  eflag   = d_in[4];
    float* out = (float*)d_out;

    char* ws = (char*)d_ws;
    const size_t partBytes = (size_t)NCHUNK * Bn * Pn * sizeof(unsigned); // 8 MiB
    unsigned* partials = (unsigned*)ws;
    Meta*     meta     = (Meta*)(ws + partBytes);

    chunk_min<<<Bn * NCHUNK, 256, 0, stream>>>(mesh_V, mesh_FN, mesh_F, points,
                                               (const unsigned char*)eflag,
                                               partials, meta);
    point_reduce<<<(Bn * Pn) / 256, 256, 0, stream>>>(partials,
                                                      (const unsigned char*)eflag,
                                                      (const int*)eflag, meta, out);
}

// Round 3
// 75.461 us; speedup vs baseline: 1.2062x; 1.1464x over previous
//
#include <hip/hip_runtime.h>
#include <math.h>

// Problem constants (from reference setup_inputs): B=4, N=8192, F=8192, P=2048
#define Bn 4
#define Nn 8192
#define Fn 8192
#define Pn 2048
#define G 64                 // face chunk-groups per batch
#define CH (Fn / G)          // 128 faces per block
#define TPB 512              // threads per block (kernel 1)
#define PPT (Pn / TPB)       // 4 points per thread
#define MIN_DIST 0.1f
#define FLTMAX_BITS 0x7F7FFFFFu

typedef float v2f __attribute__((ext_vector_type(2)));

struct Meta { float acc; int cnt; int mode; };

// ---------------- Kernel 1: fused face-precompute + per-chunk point min -----
// Grid: Bn * G = 256 blocks, 512 threads.
// Block (b,g): precompute its CH=128 faces -> (n*s, d*s) in LDS, where
// d = MIN_DIST - dot(center,n), s = ||n||. Then signed' = dot(p,n*s)+d*s
// = s*(dot(p-c,n)+MIN_DIST), and signed'^2 == signed^2*fn_sq (ref sqdist),
// sign preserved. Each thread owns 4 points (2 float2 pairs -> v_pk_fma_f32)
// and min-tracks raw fp32 bits with unsigned min: non-negative floats order
// as uints; negative signed (bits >= 0x80000000) can never beat the FLT_MAX
// init, which exactly implements where(signed<0, BIG, .) + the all-negative
// ("inside") case. Block 0 additionally probes exterior_flag storage mode and
// zero-inits the Meta accumulator used by kernel 2.
__global__ __launch_bounds__(TPB)
void chunk_min(const float* __restrict__ V, const float* __restrict__ FN,
               const int* __restrict__ Fidx, const float* __restrict__ points,
               const unsigned char* __restrict__ flags,
               unsigned* __restrict__ partials, Meta* __restrict__ meta) {
    int g = blockIdx.x & (G - 1);
    int b = blockIdx.x / G;
    int tid = threadIdx.x;

    __shared__ float4 lf[CH];    // 2 KB

    // --- face precompute (threads 0..CH-1, one face each) ---
    if (tid < CH) {
        int i = b * Fn + g * CH + tid;
        const int* fi = Fidx + (size_t)i * 3;
        int i0 = fi[0], i1 = fi[1], i2 = fi[2];
        const float* Vb = V + (size_t)b * Nn * 3;
        float cx = (Vb[i0*3+0] + Vb[i1*3+0] + Vb[i2*3+0]) * (1.0f/3.0f);
        float cy = (Vb[i0*3+1] + Vb[i1*3+1] + Vb[i2*3+1]) * (1.0f/3.0f);
        float cz = (Vb[i0*3+2] + Vb[i1*3+2] + Vb[i2*3+2]) * (1.0f/3.0f);
        const float* n = FN + (size_t)i * 3;
        float nx = n[0], ny = n[1], nz = n[2];
        float d = MIN_DIST - (cx*nx + cy*ny + cz*nz);
        float s = sqrtf(nx*nx + ny*ny + nz*nz);
        lf[tid] = make_float4(nx*s, ny*s, nz*s, d*s);
    }

    // --- load this thread's 4 points as 2 (pair) float2 vectors ---
    // pair k covers points p0 = tid + 1024*k and p1 = p0 + 512
    v2f px[PPT/2], py[PPT/2], pz[PPT/2];
    const float* pb = points + (size_t)b * Pn * 3;
#pragma unroll
    for (int k = 0; k < PPT/2; ++k) {
        int p0 = tid + 2 * TPB * k;
        int p1 = p0 + TPB;
        px[k] = (v2f){pb[p0*3+0], pb[p1*3+0]};
        py[k] = (v2f){pb[p0*3+1], pb[p1*3+1]};
        pz[k] = (v2f){pb[p0*3+2], pb[p1*3+2]};
    }
    unsigned m[PPT];
#pragma unroll
    for (int k = 0; k < PPT; ++k) m[k] = FLTMAX_BITS;

    __syncthreads();

#pragma unroll 8
    for (int j = 0; j < CH; ++j) {
        float4 f = lf[j];
        v2f fx = (v2f){f.x, f.x}, fy = (v2f){f.y, f.y},
            fz = (v2f){f.z, f.z}, fw = (v2f){f.w, f.w};
#pragma unroll
        for (int k = 0; k < PPT/2; ++k) {
#if __has_builtin(__builtin_elementwise_fma)
            v2f s = __builtin_elementwise_fma(px[k], fx,
                    __builtin_elementwise_fma(py[k], fy,
                    __builtin_elementwise_fma(pz[k], fz, fw)));
#else
            v2f s;
            s.x = fmaf(px[k].x, f.x, fmaf(py[k].x, f.y, fmaf(pz[k].x, f.z, f.w)));
            s.y = fmaf(px[k].y, f.x, fmaf(py[k].y, f.y, fmaf(pz[k].y, f.z, f.w)));
#endif
            unsigned sx = __float_as_uint(s.x);
            unsigned sy = __float_as_uint(s.y);
            m[2*k]   = sx < m[2*k]   ? sx : m[2*k];
            m[2*k+1] = sy < m[2*k+1] ? sy : m[2*k+1];
        }
    }

    // partials layout: [g][b*Pn + p] so kernel 2 reads coalesced rows
    unsigned* out = partials + (size_t)g * (Bn * Pn) + (size_t)b * Pn;
#pragma unroll
    for (int k = 0; k < PPT/2; ++k) {
        out[tid + 2 * TPB * k]       = m[2*k];
        out[tid + 2 * TPB * k + TPB] = m[2*k+1];
    }

    // --- block 0 housekeeping: storage-mode probe + meta zero-init ---
    // exterior_flag is a jax bool array; it may arrive as 1-byte bool or as
    // int32 (0/1 little-endian). If int32, every byte at offset i%4!=0 is 0.
    // Bernoulli(0.5) over 8192 elems makes the probe essentially certain.
    if (blockIdx.x == 0) {
        __shared__ int cnt;
        if (tid == 0) cnt = 0;
        __syncthreads();
        int local = 0;
        for (int i = tid; i < Bn * Pn; i += TPB)
            if ((i & 3) && flags[i]) local++;
        if (local) atomicAdd(&cnt, local);
        __syncthreads();
        if (tid == 0) {
            meta->mode = (cnt > 0) ? 1 : 0;   // 1 -> byte bools, 0 -> int32
            meta->acc = 0.0f;
            meta->cnt = 0;
        }
    }
}

// ---------------- Kernel 2: per-point reduce + flag + global mean -----------
// Grid: 64 blocks x 128 threads (one thread per point). Min over G=64 partial
// rows (coalesced), apply exterior flag, square, block-reduce, then last-block
// ticket produces the final scalar (no extra launch).
__global__ __launch_bounds__(128)
void point_reduce(const unsigned* __restrict__ partials,
                  const unsigned char* __restrict__ flagsB,
                  const int* __restrict__ flagsI,
                  Meta* __restrict__ meta, float* __restrict__ out) {
    int i = blockIdx.x * 128 + threadIdx.x;   // 0 .. B*P-1
    unsigned m = FLTMAX_BITS;
#pragma unroll 8
    for (int c = 0; c < G; ++c) {
        unsigned v = partials[(size_t)c * (Bn * Pn) + i];
        m = v < m ? v : m;
    }
    int ext = (meta->mode) ? (flagsB[i] != 0) : (flagsI[i] != 0);
    float mf = __uint_as_float(m);
    // m == FLT_MAX bits -> no face had signed >= 0 -> "inside" -> 0 (ref match)
    float val = (ext && m < FLTMAX_BITS) ? mf * mf : 0.0f;

    // wave (64-lane) shuffle reduce, then across the 2 waves via LDS
    for (int o = 32; o > 0; o >>= 1) val += __shfl_down(val, o);
    __shared__ float wsum[2];
    int lane = threadIdx.x & 63, wid = threadIdx.x >> 6;
    if (lane == 0) wsum[wid] = val;
    __syncthreads();
    if (threadIdx.x == 0) {
        float s = wsum[0] + wsum[1];
        atomicAdd(&meta->acc, s);
        __threadfence();
        int ticket = atomicAdd(&meta->cnt, 1);
        if (ticket == gridDim.x - 1) {
            // all blocks' acc-adds are fenced before their cnt-add -> visible
            float total = atomicAdd(&meta->acc, 0.0f);  // atomic read
            out[0] = total * (1.0f / (Bn * Pn));  // mean over P then B
        }
    }
}

extern "C" void kernel_launch(void* const* d_in, const int* in_sizes, int n_in,
                              void* d_out, int out_size, void* d_ws, size_t ws_size,
                              hipStream_t stream) {
    const float* mesh_V  = (const float*)d_in[0];
    const float* points  = (const float*)d_in[1];
    const float* mesh_FN = (const float*)d_in[2];
    const int*   mesh_F  = (const int*)d_in[3];
    const void*  eflag   = d_in[4];
    float* out = (float*)d_out;

    char* ws = (char*)d_ws;
    const size_t partBytes = (size_t)G * Bn * Pn * sizeof(unsigned); // 2 MiB
    unsigned* partials = (unsigned*)ws;
    Meta*     meta     = (Meta*)(ws + partBytes);

    chunk_min<<<Bn * G, TPB, 0, stream>>>(mesh_V, mesh_FN, mesh_F, points,
                                          (const unsigned char*)eflag,
                                          partials, meta);
    point_reduce<<<(Bn * Pn) / 128, 128, 0, stream>>>(partials,
                                                      (const unsigned char*)eflag,
                                                      (const int*)eflag, meta, out);
}